// Round 8
// baseline (14970.609 us; speedup 1.0000x reference)
//
#include <hip/hip_runtime.h>

typedef unsigned short u16;
typedef __bf16 bf16_t;
typedef bf16_t bf16x8 __attribute__((ext_vector_type(8)));
typedef u16 u16x8 __attribute__((ext_vector_type(8)));
typedef float f32x4 __attribute__((ext_vector_type(4)));

__device__ __forceinline__ u16 f2bf(float f) {
    unsigned u = __builtin_bit_cast(unsigned, f);
    u += 0x7fffu + ((u >> 16) & 1u);   // RNE
    return (u16)(u >> 16);
}
__device__ __forceinline__ float bf2f(u16 h) {
    unsigned u = ((unsigned)h) << 16;
    return __builtin_bit_cast(float, u);
}
__device__ __forceinline__ float fast_tanh(float x) {
    x = fminf(fmaxf(x, -20.f), 20.f);
    float e = __expf(2.f * x);
    return (e - 1.f) * __builtin_amdgcn_rcpf(e + 1.f);
}

__device__ __forceinline__ void gload_lds16(const void* g, void* l) {
    __builtin_amdgcn_global_load_lds((__attribute__((address_space(1))) void*)(g),
                                     (__attribute__((address_space(3))) void*)(l),
                                     16, 0, 0);
}

// s_waitcnt immediates: lgkmcnt=63 (no wait), expcnt=7 (no wait), vmcnt in [3:0]|[15:14]
#define WAITCNT_VM8 0x3F78   // vmcnt(8)
#define WAITCNT_VM0 0x3F70   // vmcnt(0)

// ---------------- conversion kernels ----------------

__global__ void cvt_bf16(const float* __restrict__ src, u16* __restrict__ dst, int n4) {
    int i = blockIdx.x * blockDim.x + threadIdx.x;
    if (i < n4) {
        float4 v = ((const float4*)src)[i];
        ushort4 o;
        o.x = f2bf(v.x); o.y = f2bf(v.y); o.z = f2bf(v.z); o.w = f2bf(v.w);
        ((ushort4*)dst)[i] = o;
    }
}

// W: R x C fp32  ->  WT: C x R bf16
__global__ void transpose_cvt(const float* __restrict__ W, u16* __restrict__ WT, int R, int C) {
    __shared__ float tile[32][33];
    int c0 = blockIdx.x * 32, r0 = blockIdx.y * 32;
    int tx = threadIdx.x & 31, ty = threadIdx.x >> 5;  // 32x8
#pragma unroll
    for (int i = 0; i < 32; i += 8)
        tile[ty + i][tx] = W[(size_t)(r0 + ty + i) * C + (c0 + tx)];
    __syncthreads();
#pragma unroll
    for (int i = 0; i < 32; i += 8)
        WT[(size_t)(c0 + ty + i) * R + (r0 + tx)] = f2bf(tile[tx][ty + i]);
}

// ---------------- barrier-free single-wave GEMM phase ----------------
// One wave per block (64 threads), 64x64 output tile, private double-buffered LDS,
// fine-grained s_waitcnt vmcnt(8) instead of __syncthreads (no convoying).
// Each segment: C[m,n] = sum_k A[m,k]*B[n,k]; A: 4096 x K (lda=K), B: N x K (ldb=K)
// mode 0 (FWD):  v = tanh(C + bias[n]);               write outf, outbf
// mode 1 (ERR):  v = rsrc - tanh(C);                  write outbf        (+ 0.5 v^2 if accum)
// mode 2 (UPD):  v = rsrc + 0.1*(C - bf2f(esub));     write outf, outbf
// mode 3 (UPD3): v = 0.9*rsrc + 0.1*C;                write outf, outbf  (+ 0.5 v^2 if accum)

struct Seg {
    const u16* A; const u16* B;
    const float* rsrc; const float* bias;
    const u16* esub;
    float* outf; u16* outbf;
    int K, N, blkStart, mode, accum;
};
struct Phase {
    Seg seg[3];
    int bEnd0, bEnd1;   // segment boundaries in linear block space
};

__global__ __launch_bounds__(64, 4) void pc_phase(Phase ph, float* __restrict__ errAcc) {
    // per-wave private, double-buffered: [buf][kb 0..3][row 0..63][8]
    __shared__ u16 As[2][2048];
    __shared__ u16 Bs[2][2048];

    const int bid = blockIdx.x;
    const int segi = (bid >= ph.bEnd0 ? 1 : 0) + (bid >= ph.bEnd1 ? 1 : 0);

    const int local = bid - ph.seg[segi].blkStart;
    // weight-tile-major: 64 consecutive blocks share one 64-row B (weight) tile
    const int bx = local >> 6;        // N-tile
    const int by = local & 63;        // M-tile (batch rows)
    const int K = ph.seg[segi].K;

    const int lane = threadIdx.x;     // single wave
    const int q    = lane >> 4, ln = lane & 15;

    const int rowA0 = by * 64;
    const int rowB0 = bx * 64;

    // staging sources: lane = row (64 rows), kb in 0..3 selects k-octet
    const u16* gA = ph.seg[segi].A + (size_t)(rowA0 + lane) * K;
    const u16* gB = ph.seg[segi].B + (size_t)(rowB0 + lane) * K;

    f32x4 acc[4][4];
#pragma unroll
    for (int i = 0; i < 4; ++i)
#pragma unroll
        for (int j = 0; j < 4; ++j)
            acc[i][j] = (f32x4){0.f, 0.f, 0.f, 0.f};

    const int niter = K >> 5;

    // prologue: stage tile 0 into buffer 0 (8 DMA loads, 1 KB each)
#pragma unroll
    for (int kb = 0; kb < 4; ++kb) {
        gload_lds16(gA + kb * 8, &As[0][kb * 512]);
        gload_lds16(gB + kb * 8, &Bs[0][kb * 512]);
    }

    // fragment read bases (this wave's quadrant: q = kb)
    const u16* asrd = &As[0][q * 512 + ln * 8];
    const u16* bsrd = &Bs[0][q * 512 + ln * 8];

    for (int k = 0; k < niter; ++k) {
        const int cur = k & 1;
        if (k + 1 < niter) {
            // prefetch tile k+1 into other buffer, then wait for tile k only
            const int nb = cur ^ 1;
            const int k0 = (k + 1) << 5;
#pragma unroll
            for (int kb = 0; kb < 4; ++kb) {
                gload_lds16(gA + k0 + kb * 8, &As[nb][kb * 512]);
                gload_lds16(gB + k0 + kb * 8, &Bs[nb][kb * 512]);
            }
            __builtin_amdgcn_s_waitcnt(WAITCNT_VM8);   // tile k landed; k+1 in flight
        } else {
            __builtin_amdgcn_s_waitcnt(WAITCNT_VM0);   // last tile: full drain
        }

        const u16* as = asrd + cur * 2048;
        const u16* bs = bsrd + cur * 2048;
        bf16x8 a[4], b[4];
#pragma unroll
        for (int mt = 0; mt < 4; ++mt)
            a[mt] = __builtin_bit_cast(bf16x8, *(const u16x8*)&as[mt * 128]);
#pragma unroll
        for (int nt = 0; nt < 4; ++nt)
            b[nt] = __builtin_bit_cast(bf16x8, *(const u16x8*)&bs[nt * 128]);
#pragma unroll
        for (int mt = 0; mt < 4; ++mt)
#pragma unroll
            for (int nt = 0; nt < 4; ++nt)
                acc[mt][nt] = __builtin_amdgcn_mfma_f32_16x16x32_bf16(
                    a[mt], b[nt], acc[mt][nt], 0, 0, 0);
    }

    // epilogue: fetch remaining segment params (not live during K-loop)
    const int N = ph.seg[segi].N;
    const int mode = ph.seg[segi].mode;
    const int accum = ph.seg[segi].accum;
    const float* rsrc = ph.seg[segi].rsrc;
    const float* bias = ph.seg[segi].bias;
    const u16* esub = ph.seg[segi].esub;
    float* outf = ph.seg[segi].outf;
    u16* outbf = ph.seg[segi].outbf;

    // C/D layout: col = lane&15 (n), row = q*4 + reg (m)
    float lsum = 0.f;
    const int ncol0 = rowB0 + ln;
#pragma unroll
    for (int mt = 0; mt < 4; ++mt) {
#pragma unroll
        for (int r = 0; r < 4; ++r) {
            int m = rowA0 + mt * 16 + q * 4 + r;
            size_t offm = (size_t)m * N;
#pragma unroll
            for (int nt = 0; nt < 4; ++nt) {
                int n = ncol0 + nt * 16;
                size_t idx = offm + n;
                float c = acc[mt][nt][r];
                if (mode == 0) {
                    float v = fast_tanh(c + bias[n]);
                    outf[idx] = v; outbf[idx] = f2bf(v);
                } else if (mode == 1) {
                    float v = rsrc[idx] - fast_tanh(c);
                    outbf[idx] = f2bf(v);
                    if (accum) lsum += v * v;
                } else if (mode == 2) {
                    float v = rsrc[idx] + 0.1f * (c - bf2f(esub[idx]));
                    outf[idx] = v; outbf[idx] = f2bf(v);
                } else {
                    float v = 0.9f * rsrc[idx] + 0.1f * c;
                    outf[idx] = v; outbf[idx] = f2bf(v);
                    if (accum) lsum += v * v;
                }
            }
        }
    }

    if (accum) {
        lsum *= 0.5f;
#pragma unroll
        for (int o = 32; o > 0; o >>= 1) lsum += __shfl_down(lsum, o);
        if (lane == 0) atomicAdd(errAcc, lsum);
    }
}

// ---------------- host ----------------

extern "C" void kernel_launch(void* const* d_in, const int* in_sizes, int n_in,
                              void* d_out, int out_size, void* d_ws, size_t ws_size,
                              hipStream_t stream) {
    const float* x  = (const float*)d_in[0];
    const float* W0 = (const float*)d_in[1];
    const float* b0 = (const float*)d_in[2];
    const float* W1 = (const float*)d_in[3];
    const float* b1 = (const float*)d_in[4];
    const float* W2 = (const float*)d_in[5];
    const float* b2 = (const float*)d_in[6];

    const int Bz = 4096;  // batch

    char* ws = (char*)d_ws;
    size_t off = 0;
    auto alloc = [&](size_t bytes) -> char* {
        char* p = ws + off;
        off += (bytes + 255) & ~(size_t)255;
        return p;
    };

    float* r1f = (float*)alloc((size_t)Bz * 2048 * 4);
    float* r2f = (float*)alloc((size_t)Bz * 2048 * 4);
    u16*   r1b = (u16*)  alloc((size_t)Bz * 2048 * 2);
    u16*   r2b = (u16*)  alloc((size_t)Bz * 2048 * 2);
    u16*   r3b = (u16*)  alloc((size_t)Bz * 512 * 2);
    u16*   e0b = (u16*)  alloc((size_t)Bz * 1024 * 2);
    u16*   e1b = (u16*)  alloc((size_t)Bz * 2048 * 2);
    u16*   e2b = (u16*)  alloc((size_t)Bz * 2048 * 2);
    u16*   xb  = (u16*)  alloc((size_t)Bz * 1024 * 2);
    u16*   W0b = (u16*)  alloc((size_t)2048 * 1024 * 2);
    u16*   W0t = (u16*)  alloc((size_t)1024 * 2048 * 2);
    u16*   W1b = (u16*)  alloc((size_t)2048 * 2048 * 2);
    u16*   W1t = (u16*)  alloc((size_t)2048 * 2048 * 2);
    u16*   W2b = (u16*)  alloc((size_t)512 * 2048 * 2);
    u16*   W2t = (u16*)  alloc((size_t)2048 * 512 * 2);

    float* r3f    = (float*)d_out;            // 4096 x 512
    float* errAcc = ((float*)d_out) + (size_t)Bz * 512;

    cvt_bf16<<<(Bz * 1024 / 4) / 256, 256, 0, stream>>>(x,  xb,  Bz * 1024 / 4);
    cvt_bf16<<<(2048 * 1024 / 4) / 256, 256, 0, stream>>>(W0, W0b, 2048 * 1024 / 4);
    cvt_bf16<<<(2048 * 2048 / 4) / 256, 256, 0, stream>>>(W1, W1b, 2048 * 2048 / 4);
    cvt_bf16<<<(512 * 2048 / 4) / 256, 256, 0, stream>>>(W2, W2b, 512 * 2048 / 4);
    transpose_cvt<<<dim3(1024 / 32, 2048 / 32), 256, 0, stream>>>(W0, W0t, 2048, 1024);
    transpose_cvt<<<dim3(2048 / 32, 2048 / 32), 256, 0, stream>>>(W1, W1t, 2048, 2048);
    transpose_cvt<<<dim3(2048 / 32, 512 / 32),  256, 0, stream>>>(W2, W2t, 512, 2048);

    hipMemsetAsync(errAcc, 0, 4, stream);

    auto mkseg = [&](const u16* A, const u16* B, int K, int N,
                     const float* rsrc, const float* bias, const u16* esub,
                     float* outf, u16* outbf, int mode, int accum, int blkStart) {
        Seg s;
        s.A = A; s.B = B; s.rsrc = rsrc; s.bias = bias; s.esub = esub;
        s.outf = outf; s.outbf = outbf;
        s.K = K; s.N = N; s.blkStart = blkStart;
        s.mode = mode; s.accum = accum;
        return s;
    };
    auto nblk = [&](int N) { return (N / 64) * (Bz / 64); };

    auto launch1 = [&](Seg s0) {
        Phase ph;
        int b0 = nblk(s0.N);
        ph.seg[0] = s0; ph.seg[1] = s0; ph.seg[2] = s0;
        ph.bEnd0 = b0; ph.bEnd1 = b0;
        pc_phase<<<b0, 64, 0, stream>>>(ph, errAcc);
    };
    auto launch3 = [&](Seg s0, Seg s1, Seg s2) {
        Phase ph;
        int b0 = nblk(s0.N), b1 = nblk(s1.N), b2 = nblk(s2.N);
        s1.blkStart = b0; s2.blkStart = b0 + b1;
        ph.seg[0] = s0; ph.seg[1] = s1; ph.seg[2] = s2;
        ph.bEnd0 = b0; ph.bEnd1 = b0 + b1;
        pc_phase<<<b0 + b1 + b2, 64, 0, stream>>>(ph, errAcc);
    };

    // forward init (sequential dependency)
    launch1(mkseg(xb,  W0b, 1024, 2048, nullptr, b0, nullptr, r1f, r1b, 0, 0, 0));
    launch1(mkseg(r1b, W1b, 2048, 2048, nullptr, b1, nullptr, r2f, r2b, 0, 0, 0));
    launch1(mkseg(r2b, W2b, 2048, 512,  nullptr, b2, nullptr, r3f, r3b, 0, 0, 0));

    // 20 relaxation steps: fused error phase, fused update phase
    for (int s = 0; s < 20; ++s) {
        int last = (s == 19) ? 1 : 0;
        // errors (independent)
        launch3(mkseg(r2b, W1t, 2048, 2048, r1f, nullptr, nullptr, nullptr, e1b, 1, 0, 0),
                mkseg(r1b, W0t, 2048, 1024, x,   nullptr, nullptr, nullptr, e0b, 1, 0, 0),
                mkseg(r3b, W2t, 512,  2048, r2f, nullptr, nullptr, nullptr, e2b, 1, 0, 0));
        // updates (independent)
        launch3(mkseg(e1b, W1b, 2048, 2048, r2f, nullptr, e2b, r2f, r2b, 2, 0, 0),
                mkseg(e2b, W2b, 2048, 512,  r3f, nullptr, nullptr, r3f, r3b, 3, last, 0),
                mkseg(e0b, W0b, 1024, 2048, r1f, nullptr, e1b, r1f, r1b, 2, 0, 0));
    }

    // final errors with 0.5*sum(e^2) accumulation (r3^2 added by last UPD3)
    launch3(mkseg(r2b, W1t, 2048, 2048, r1f, nullptr, nullptr, nullptr, e1b, 1, 1, 0),
            mkseg(r1b, W0t, 2048, 1024, x,   nullptr, nullptr, nullptr, e0b, 1, 1, 0),
            mkseg(r3b, W2t, 512,  2048, r2f, nullptr, nullptr, nullptr, e2b, 1, 1, 0));
}

// Round 9
// 9113.425 us; speedup vs baseline: 1.6427x; 1.6427x over previous
//
#include <hip/hip_runtime.h>

typedef unsigned short u16;
typedef __bf16 bf16_t;
typedef bf16_t bf16x8 __attribute__((ext_vector_type(8)));
typedef u16 u16x8 __attribute__((ext_vector_type(8)));
typedef float f32x4 __attribute__((ext_vector_type(4)));

__device__ __forceinline__ u16 f2bf(float f) {
    unsigned u = __builtin_bit_cast(unsigned, f);
    u += 0x7fffu + ((u >> 16) & 1u);   // RNE
    return (u16)(u >> 16);
}
__device__ __forceinline__ float bf2f(u16 h) {
    unsigned u = ((unsigned)h) << 16;
    return __builtin_bit_cast(float, u);
}
__device__ __forceinline__ float fast_tanh(float x) {
    x = fminf(fmaxf(x, -20.f), 20.f);
    float e = __expf(2.f * x);
    return (e - 1.f) * __builtin_amdgcn_rcpf(e + 1.f);
}

__device__ __forceinline__ void gload_lds16(const void* g, void* l) {
    __builtin_amdgcn_global_load_lds((__attribute__((address_space(1))) void*)(g),
                                     (__attribute__((address_space(3))) void*)(l),
                                     16, 0, 0);
}

// ---------------- conversion kernels ----------------

__global__ void cvt_bf16(const float* __restrict__ src, u16* __restrict__ dst, int n4) {
    int i = blockIdx.x * blockDim.x + threadIdx.x;
    if (i < n4) {
        float4 v = ((const float4*)src)[i];
        ushort4 o;
        o.x = f2bf(v.x); o.y = f2bf(v.y); o.z = f2bf(v.z); o.w = f2bf(v.w);
        ((ushort4*)dst)[i] = o;
    }
}

// W: R x C fp32  ->  WT: C x R bf16
__global__ void transpose_cvt(const float* __restrict__ W, u16* __restrict__ WT, int R, int C) {
    __shared__ float tile[32][33];
    int c0 = blockIdx.x * 32, r0 = blockIdx.y * 32;
    int tx = threadIdx.x & 31, ty = threadIdx.x >> 5;  // 32x8
#pragma unroll
    for (int i = 0; i < 32; i += 8)
        tile[ty + i][tx] = W[(size_t)(r0 + ty + i) * C + (c0 + tx)];
    __syncthreads();
#pragma unroll
    for (int i = 0; i < 32; i += 8)
        WT[(size_t)(c0 + ty + i) * R + (r0 + tx)] = f2bf(tile[tx][ty + i]);
}

// ---------------- segmented fused NT GEMM phase ----------------
// R6 structure (BK=32, single buffer, 2 barriers, reg diet) plus:
//  - XCD swizzle: blocks sharing a weight tile land on one XCD (W-tile in L2)
//  - K-ring stagger: co-resident blocks start the K-loop at different offsets
//    (desyncs their DMA bursts; fp32 acc reorder only)
// Each segment: C[m,n] = sum_k A[m,k]*B[n,k]; A: 4096 x K (lda=K), B: N x K (ldb=K)
// mode 0 (FWD):  v = tanh(C + bias[n]);               write outf, outbf
// mode 1 (ERR):  v = rsrc - tanh(C);                  write outbf        (+ 0.5 v^2 if accum)
// mode 2 (UPD):  v = rsrc + 0.1*(C - bf2f(esub));     write outf, outbf
// mode 3 (UPD3): v = 0.9*rsrc + 0.1*C;                write outf, outbf  (+ 0.5 v^2 if accum)

struct Seg {
    const u16* A; const u16* B;
    const float* rsrc; const float* bias;
    const u16* esub;
    float* outf; u16* outbf;
    int K, N, blkStart, mode, accum;
};
struct Phase {
    Seg seg[3];
    int bEnd0, bEnd1;   // segment boundaries in LOGICAL block space
};

__global__ __launch_bounds__(256, 4) void pc_phase(Phase ph, float* __restrict__ errAcc) {
    __shared__ u16 As[4096];   // [kb 0..3][row 0..127][8]
    __shared__ u16 Bs[4096];
    __shared__ float red[4];

    // XCD swizzle: physical bids with the same (bid & 7) go to the same XCD;
    // map them to CONSECUTIVE logical ids so blocks sharing a weight tile share an XCD L2.
    const int p = blockIdx.x;
    const int bid = (p & 7) * ((int)gridDim.x >> 3) + (p >> 3);
    const int segi = (bid >= ph.bEnd0 ? 1 : 0) + (bid >= ph.bEnd1 ? 1 : 0);

    const int local = bid - ph.seg[segi].blkStart;
    // weight-tile-major ordering: 32 consecutive logical blocks share one B (weight) tile
    const int bx = local >> 5;        // N-tile (weight rows)
    const int by = local & 31;        // M-tile (batch rows)
    const int K = ph.seg[segi].K;

    const int tid  = threadIdx.x;
    const int wave = tid >> 6, lane = tid & 63;
    const int q    = lane >> 4, ln = lane & 15;
    const int wrow = (wave >> 1) * 64, wcol = (wave & 1) * 64;

    const int rowA0 = by * 128;
    const int rowB0 = bx * 128;

    const u16* gA0 = ph.seg[segi].A + (size_t)(rowA0 + lane) * K + wave * 8;
    const u16* gA1 = gA0 + (size_t)64 * K;
    const u16* gB0 = ph.seg[segi].B + (size_t)(rowB0 + lane) * K + wave * 8;
    const u16* gB1 = gB0 + (size_t)64 * K;
    u16* lA0 = &As[wave * 1024];
    u16* lA1 = &As[wave * 1024 + 512];
    u16* lB0 = &Bs[wave * 1024];
    u16* lB1 = &Bs[wave * 1024 + 512];

    f32x4 acc[4][4];
#pragma unroll
    for (int i = 0; i < 4; ++i)
#pragma unroll
        for (int j = 0; j < 4; ++j)
            acc[i][j] = (f32x4){0.f, 0.f, 0.f, 0.f};

    const u16* asrd = &As[q * 1024 + (wrow + ln) * 8];
    const u16* bsrd = &Bs[q * 1024 + (wcol + ln) * 8];

    const int niter = K >> 5;
    // stagger: co-resident blocks (physical bids differing by 256) start the
    // K-ring at offsets 0, 1/4, 1/2, 3/4 of niter (niter is 16/32/64 -> /4 exact)
    const int koff = ((p >> 8) & 3) * (niter >> 2);

    for (int j = 0; j < niter; ++j) {
        int k = j + koff; if (k >= niter) k -= niter;
        const size_t ko = (size_t)k * 32;
        gload_lds16(gA0 + ko, lA0);
        gload_lds16(gA1 + ko, lA1);
        gload_lds16(gB0 + ko, lB0);
        gload_lds16(gB1 + ko, lB1);
        __syncthreads();

        bf16x8 a[4], b[4];
#pragma unroll
        for (int mt = 0; mt < 4; ++mt)
            a[mt] = __builtin_bit_cast(bf16x8, *(const u16x8*)&asrd[mt * 128]);
#pragma unroll
        for (int nt = 0; nt < 4; ++nt)
            b[nt] = __builtin_bit_cast(bf16x8, *(const u16x8*)&bsrd[nt * 128]);
#pragma unroll
        for (int mt = 0; mt < 4; ++mt)
#pragma unroll
            for (int nt = 0; nt < 4; ++nt)
                acc[mt][nt] = __builtin_amdgcn_mfma_f32_16x16x32_bf16(
                    a[mt], b[nt], acc[mt][nt], 0, 0, 0);
        __syncthreads();
    }

    // epilogue: fetch remaining segment params now (not live during K-loop)
    const int N = ph.seg[segi].N;
    const int mode = ph.seg[segi].mode;
    const int accum = ph.seg[segi].accum;
    const float* rsrc = ph.seg[segi].rsrc;
    const float* bias = ph.seg[segi].bias;
    const u16* esub = ph.seg[segi].esub;
    float* outf = ph.seg[segi].outf;
    u16* outbf = ph.seg[segi].outbf;

    // C/D layout: col = lane&15 (n), row = q*4 + reg (m)
    float lsum = 0.f;
    const int ncol0 = rowB0 + wcol + ln;
#pragma unroll
    for (int mt = 0; mt < 4; ++mt) {
#pragma unroll
        for (int r = 0; r < 4; ++r) {
            int m = rowA0 + wrow + mt * 16 + q * 4 + r;
            size_t offm = (size_t)m * N;
#pragma unroll
            for (int nt = 0; nt < 4; ++nt) {
                int n = ncol0 + nt * 16;
                size_t idx = offm + n;
                float c = acc[mt][nt][r];
                if (mode == 0) {
                    float v = fast_tanh(c + bias[n]);
                    outf[idx] = v; outbf[idx] = f2bf(v);
                } else if (mode == 1) {
                    float v = rsrc[idx] - fast_tanh(c);
                    outbf[idx] = f2bf(v);
                    if (accum) lsum += v * v;
                } else if (mode == 2) {
                    float v = rsrc[idx] + 0.1f * (c - bf2f(esub[idx]));
                    outf[idx] = v; outbf[idx] = f2bf(v);
                } else {
                    float v = 0.9f * rsrc[idx] + 0.1f * c;
                    outf[idx] = v; outbf[idx] = f2bf(v);
                    if (accum) lsum += v * v;
                }
            }
        }
    }

    if (accum) {
        lsum *= 0.5f;
#pragma unroll
        for (int o = 32; o > 0; o >>= 1) lsum += __shfl_down(lsum, o);
        if (lane == 0) red[wave] = lsum;
        __syncthreads();
        if (tid == 0) atomicAdd(errAcc, red[0] + red[1] + red[2] + red[3]);
    }
}

// ---------------- host ----------------

extern "C" void kernel_launch(void* const* d_in, const int* in_sizes, int n_in,
                              void* d_out, int out_size, void* d_ws, size_t ws_size,
                              hipStream_t stream) {
    const float* x  = (const float*)d_in[0];
    const float* W0 = (const float*)d_in[1];
    const float* b0 = (const float*)d_in[2];
    const float* W1 = (const float*)d_in[3];
    const float* b1 = (const float*)d_in[4];
    const float* W2 = (const float*)d_in[5];
    const float* b2 = (const float*)d_in[6];

    const int Bz = 4096;  // batch

    char* ws = (char*)d_ws;
    size_t off = 0;
    auto alloc = [&](size_t bytes) -> char* {
        char* p = ws + off;
        off += (bytes + 255) & ~(size_t)255;
        return p;
    };

    float* r1f = (float*)alloc((size_t)Bz * 2048 * 4);
    float* r2f = (float*)alloc((size_t)Bz * 2048 * 4);
    u16*   r1b = (u16*)  alloc((size_t)Bz * 2048 * 2);
    u16*   r2b = (u16*)  alloc((size_t)Bz * 2048 * 2);
    u16*   r3b = (u16*)  alloc((size_t)Bz * 512 * 2);
    u16*   e0b = (u16*)  alloc((size_t)Bz * 1024 * 2);
    u16*   e1b = (u16*)  alloc((size_t)Bz * 2048 * 2);
    u16*   e2b = (u16*)  alloc((size_t)Bz * 2048 * 2);
    u16*   xb  = (u16*)  alloc((size_t)Bz * 1024 * 2);
    u16*   W0b = (u16*)  alloc((size_t)2048 * 1024 * 2);
    u16*   W0t = (u16*)  alloc((size_t)1024 * 2048 * 2);
    u16*   W1b = (u16*)  alloc((size_t)2048 * 2048 * 2);
    u16*   W1t = (u16*)  alloc((size_t)2048 * 2048 * 2);
    u16*   W2b = (u16*)  alloc((size_t)512 * 2048 * 2);
    u16*   W2t = (u16*)  alloc((size_t)2048 * 512 * 2);

    float* r3f    = (float*)d_out;            // 4096 x 512
    float* errAcc = ((float*)d_out) + (size_t)Bz * 512;

    cvt_bf16<<<(Bz * 1024 / 4) / 256, 256, 0, stream>>>(x,  xb,  Bz * 1024 / 4);
    cvt_bf16<<<(2048 * 1024 / 4) / 256, 256, 0, stream>>>(W0, W0b, 2048 * 1024 / 4);
    cvt_bf16<<<(2048 * 2048 / 4) / 256, 256, 0, stream>>>(W1, W1b, 2048 * 2048 / 4);
    cvt_bf16<<<(512 * 2048 / 4) / 256, 256, 0, stream>>>(W2, W2b, 512 * 2048 / 4);
    transpose_cvt<<<dim3(1024 / 32, 2048 / 32), 256, 0, stream>>>(W0, W0t, 2048, 1024);
    transpose_cvt<<<dim3(2048 / 32, 2048 / 32), 256, 0, stream>>>(W1, W1t, 2048, 2048);
    transpose_cvt<<<dim3(2048 / 32, 512 / 32),  256, 0, stream>>>(W2, W2t, 512, 2048);

    hipMemsetAsync(errAcc, 0, 4, stream);

    auto mkseg = [&](const u16* A, const u16* B, int K, int N,
                     const float* rsrc, const float* bias, const u16* esub,
                     float* outf, u16* outbf, int mode, int accum, int blkStart) {
        Seg s;
        s.A = A; s.B = B; s.rsrc = rsrc; s.bias = bias; s.esub = esub;
        s.outf = outf; s.outbf = outbf;
        s.K = K; s.N = N; s.blkStart = blkStart;
        s.mode = mode; s.accum = accum;
        return s;
    };
    auto nblk = [&](int N) { return (N / 128) * (Bz / 128); };

    auto launch1 = [&](Seg s0) {
        Phase ph;
        int b0 = nblk(s0.N);
        ph.seg[0] = s0; ph.seg[1] = s0; ph.seg[2] = s0;
        ph.bEnd0 = b0; ph.bEnd1 = b0;
        pc_phase<<<b0, 256, 0, stream>>>(ph, errAcc);
    };
    auto launch3 = [&](Seg s0, Seg s1, Seg s2) {
        Phase ph;
        int b0 = nblk(s0.N), b1 = nblk(s1.N), b2 = nblk(s2.N);
        s1.blkStart = b0; s2.blkStart = b0 + b1;
        ph.seg[0] = s0; ph.seg[1] = s1; ph.seg[2] = s2;
        ph.bEnd0 = b0; ph.bEnd1 = b0 + b1;
        pc_phase<<<b0 + b1 + b2, 256, 0, stream>>>(ph, errAcc);
    };

    // forward init (sequential dependency)
    launch1(mkseg(xb,  W0b, 1024, 2048, nullptr, b0, nullptr, r1f, r1b, 0, 0, 0));
    launch1(mkseg(r1b, W1b, 2048, 2048, nullptr, b1, nullptr, r2f, r2b, 0, 0, 0));
    launch1(mkseg(r2b, W2b, 2048, 512,  nullptr, b2, nullptr, r3f, r3b, 0, 0, 0));

    // 20 relaxation steps: fused error phase, fused update phase
    for (int s = 0; s < 20; ++s) {
        int last = (s == 19) ? 1 : 0;
        // errors (independent)
        launch3(mkseg(r2b, W1t, 2048, 2048, r1f, nullptr, nullptr, nullptr, e1b, 1, 0, 0),
                mkseg(r1b, W0t, 2048, 1024, x,   nullptr, nullptr, nullptr, e0b, 1, 0, 0),
                mkseg(r3b, W2t, 512,  2048, r2f, nullptr, nullptr, nullptr, e2b, 1, 0, 0));
        // updates (independent)
        launch3(mkseg(e1b, W1b, 2048, 2048, r2f, nullptr, e2b, r2f, r2b, 2, 0, 0),
                mkseg(e2b, W2b, 2048, 512,  r3f, nullptr, nullptr, r3f, r3b, 3, last, 0),
                mkseg(e0b, W0b, 1024, 2048, r1f, nullptr, e1b, r1f, r1b, 2, 0, 0));
    }

    // final errors with 0.5*sum(e^2) accumulation (r3^2 added by last UPD3)
    launch3(mkseg(r2b, W1t, 2048, 2048, r1f, nullptr, nullptr, nullptr, e1b, 1, 1, 0),
            mkseg(r1b, W0t, 2048, 1024, x,   nullptr, nullptr, nullptr, e0b, 1, 1, 0),
            mkseg(r3b, W2t, 512,  2048, r2f, nullptr, nullptr, nullptr, e2b, 1, 1, 0));
}

// Round 10
// 4106.128 us; speedup vs baseline: 3.6459x; 2.2195x over previous
//
#include <hip/hip_runtime.h>

typedef unsigned short u16;
typedef __bf16 bf16_t;
typedef bf16_t bf16x8 __attribute__((ext_vector_type(8)));
typedef u16 u16x8 __attribute__((ext_vector_type(8)));
typedef float f32x4 __attribute__((ext_vector_type(4)));

__device__ __forceinline__ u16 f2bf(float f) {
    unsigned u = __builtin_bit_cast(unsigned, f);
    u += 0x7fffu + ((u >> 16) & 1u);   // RNE
    return (u16)(u >> 16);
}
__device__ __forceinline__ float bf2f(u16 h) {
    unsigned u = ((unsigned)h) << 16;
    return __builtin_bit_cast(float, u);
}
__device__ __forceinline__ float fast_tanh(float x) {
    x = fminf(fmaxf(x, -20.f), 20.f);
    float e = __expf(2.f * x);
    return (e - 1.f) * __builtin_amdgcn_rcpf(e + 1.f);
}

__device__ __forceinline__ void gload_lds16(const void* g, void* l) {
    __builtin_amdgcn_global_load_lds((__attribute__((address_space(1))) void*)(g),
                                     (__attribute__((address_space(3))) void*)(l),
                                     16, 0, 0);
}

// Blocked layout for a row-major M x N matrix (M,N multiples of 128/32):
// tile (rb = m>>7, cb = n>>5) stored contiguously (4096 elems = 8 KB), tiles
// ordered rb-major; tile interior = [kb = (n>>3)&3][row = m&127][n&7] — the
// exact LDS image the GEMM stages, so staging loads are 1 KB CONTIGUOUS.
__device__ __forceinline__ size_t boff(int m, int n, int N) {
    return (size_t)((m >> 7) * (N >> 5) + (n >> 5)) * 4096
         + (size_t)((((n >> 3) & 3) << 10) + ((m & 127) << 3) + (n & 7));
}

// ---------------- conversion kernels ----------------

__global__ void cvt_bf16(const float* __restrict__ src, u16* __restrict__ dst, int n4) {
    int i = blockIdx.x * blockDim.x + threadIdx.x;
    if (i < n4) {
        float4 v = ((const float4*)src)[i];
        ushort4 o;
        o.x = f2bf(v.x); o.y = f2bf(v.y); o.z = f2bf(v.z); o.w = f2bf(v.w);
        ((ushort4*)dst)[i] = o;
    }
}

// W: R x C fp32  ->  WT: C x R bf16 (row-major)
__global__ void transpose_cvt(const float* __restrict__ W, u16* __restrict__ WT, int R, int C) {
    __shared__ float tile[32][33];
    int c0 = blockIdx.x * 32, r0 = blockIdx.y * 32;
    int tx = threadIdx.x & 31, ty = threadIdx.x >> 5;  // 32x8
#pragma unroll
    for (int i = 0; i < 32; i += 8)
        tile[ty + i][tx] = W[(size_t)(r0 + ty + i) * C + (c0 + tx)];
    __syncthreads();
#pragma unroll
    for (int i = 0; i < 32; i += 8)
        WT[(size_t)(c0 + ty + i) * R + (r0 + tx)] = f2bf(tile[tx][ty + i]);
}

// row-major bf16 (M x K) -> blocked layout. grid = (M/128)*(K/32), 256 thr.
__global__ void blockify(const u16* __restrict__ src, u16* __restrict__ dst, int K) {
    const int nk = K >> 5;
    const int rb = blockIdx.x / nk, cb = blockIdx.x % nk;
    const int t = threadIdx.x;
    const int kloc = (t & 7) * 4;                 // 0,4,...,28
    u16* d = dst + (size_t)blockIdx.x * 4096 + ((kloc >> 3) << 10) + (kloc & 7);
    const u16* s = src + (size_t)(rb * 128) * K + cb * 32 + kloc;
#pragma unroll
    for (int p = 0; p < 4; ++p) {
        int row = (t >> 3) + p * 32;
        *(ushort4*)(d + row * 8) = *(const ushort4*)(s + (size_t)row * K);
    }
}

// ---------------- segmented fused NT GEMM phase (blocked operands) ----------------
// C[m,n] = sum_k A[m,k]*B[n,k]; A: 4096 x K blocked, B: N x K blocked.
// Staging: per wave 4 x 1 KB CONTIGUOUS global_load_lds (sequential cache lines).
// mode 0 (FWD):  v = tanh(C + bias[n]);               write outf, outbf
// mode 1 (ERR):  v = rsrc - tanh(C);                  write outbf        (+ 0.5 v^2 if accum)
// mode 2 (UPD):  v = rsrc + 0.1*(C - bf2f(esub));     write outf, outbf
// mode 3 (UPD3): v = 0.9*rsrc + 0.1*C;                write outf, outbf  (+ 0.5 v^2 if accum)
// f32 buffers (rsrc/outf/bias) stay row-major; bf16 buffers (A/B/esub/outbf) blocked.

struct Seg {
    const u16* A; const u16* B;
    const float* rsrc; const float* bias;
    const u16* esub;
    float* outf; u16* outbf;
    int K, N, blkStart, mode, accum;
};
struct Phase {
    Seg seg[3];
    int bEnd0, bEnd1;
};

__global__ __launch_bounds__(256, 4) void pc_phase(Phase ph, float* __restrict__ errAcc) {
    __shared__ u16 As[4096];   // [kb 0..3][row 0..127][8]
    __shared__ u16 Bs[4096];
    __shared__ float red[4];

    const int bid = blockIdx.x;
    const int segi = (bid >= ph.bEnd0 ? 1 : 0) + (bid >= ph.bEnd1 ? 1 : 0);

    const int local = bid - ph.seg[segi].blkStart;
    // weight-tile-major: 32 consecutive blocks share one B (weight) tile row
    const int bx = local >> 5;        // N-tile
    const int by = local & 31;        // M-tile (batch rows)
    const int K = ph.seg[segi].K;

    const int tid  = threadIdx.x;
    const int wave = tid >> 6, lane = tid & 63;
    const int q    = lane >> 4, ln = lane & 15;
    const int wrow = (wave >> 1) * 64, wcol = (wave & 1) * 64;

    const int nk = K >> 5;
    // contiguous staging sources: wave w copies tile bytes [w*2 KB, (w+1)*2 KB)
    const u16* tA = ph.seg[segi].A + (size_t)by * nk * 4096 + wave * 1024 + lane * 8;
    const u16* tB = ph.seg[segi].B + (size_t)bx * nk * 4096 + wave * 1024 + lane * 8;
    u16* lA0 = &As[wave * 1024];
    u16* lA1 = &As[wave * 1024 + 512];
    u16* lB0 = &Bs[wave * 1024];
    u16* lB1 = &Bs[wave * 1024 + 512];

    f32x4 acc[4][4];
#pragma unroll
    for (int i = 0; i < 4; ++i)
#pragma unroll
        for (int j = 0; j < 4; ++j)
            acc[i][j] = (f32x4){0.f, 0.f, 0.f, 0.f};

    const u16* asrd = &As[q * 1024 + (wrow + ln) * 8];
    const u16* bsrd = &Bs[q * 1024 + (wcol + ln) * 8];

    for (int k = 0; k < nk; ++k) {
        const size_t kb = (size_t)k * 4096;
        gload_lds16(tA + kb, lA0);
        gload_lds16(tA + kb + 512, lA1);
        gload_lds16(tB + kb, lB0);
        gload_lds16(tB + kb + 512, lB1);
        __syncthreads();

        bf16x8 a[4], b[4];
#pragma unroll
        for (int mt = 0; mt < 4; ++mt)
            a[mt] = __builtin_bit_cast(bf16x8, *(const u16x8*)&asrd[mt * 128]);
#pragma unroll
        for (int nt = 0; nt < 4; ++nt)
            b[nt] = __builtin_bit_cast(bf16x8, *(const u16x8*)&bsrd[nt * 128]);
#pragma unroll
        for (int mt = 0; mt < 4; ++mt)
#pragma unroll
            for (int nt = 0; nt < 4; ++nt)
                acc[mt][nt] = __builtin_amdgcn_mfma_f32_16x16x32_bf16(
                    a[mt], b[nt], acc[mt][nt], 0, 0, 0);
        __syncthreads();
    }

    // epilogue (params fetched after K-loop to keep loop-live regs low)
    const int N = ph.seg[segi].N;
    const int mode = ph.seg[segi].mode;
    const int accum = ph.seg[segi].accum;
    const float* rsrc = ph.seg[segi].rsrc;
    const float* bias = ph.seg[segi].bias;
    const u16* esub = ph.seg[segi].esub;
    float* outf = ph.seg[segi].outf;
    u16* outbf = ph.seg[segi].outbf;

    const int rowA0 = by * 128;
    const int rowB0 = bx * 128;

    // C/D layout: col = lane&15 (n), row = q*4 + reg (m)
    float lsum = 0.f;
    const int ncol0 = rowB0 + wcol + ln;
#pragma unroll
    for (int mt = 0; mt < 4; ++mt) {
#pragma unroll
        for (int r = 0; r < 4; ++r) {
            int m = rowA0 + wrow + mt * 16 + q * 4 + r;
            size_t offm = (size_t)m * N;
#pragma unroll
            for (int nt = 0; nt < 4; ++nt) {
                int n = ncol0 + nt * 16;
                size_t idx = offm + n;          // row-major (f32 buffers)
                size_t bidx = boff(m, n, N);    // blocked (bf16 buffers)
                float c = acc[mt][nt][r];
                if (mode == 0) {
                    float v = fast_tanh(c + bias[n]);
                    outf[idx] = v; outbf[bidx] = f2bf(v);
                } else if (mode == 1) {
                    float v = rsrc[idx] - fast_tanh(c);
                    outbf[bidx] = f2bf(v);
                    if (accum) lsum += v * v;
                } else if (mode == 2) {
                    float v = rsrc[idx] + 0.1f * (c - bf2f(esub[bidx]));
                    outf[idx] = v; outbf[bidx] = f2bf(v);
                } else {
                    float v = 0.9f * rsrc[idx] + 0.1f * c;
                    outf[idx] = v; outbf[bidx] = f2bf(v);
                    if (accum) lsum += v * v;
                }
            }
        }
    }

    if (accum) {
        lsum *= 0.5f;
#pragma unroll
        for (int o = 32; o > 0; o >>= 1) lsum += __shfl_down(lsum, o);
        if (lane == 0) red[wave] = lsum;
        __syncthreads();
        if (tid == 0) atomicAdd(errAcc, red[0] + red[1] + red[2] + red[3]);
    }
}

// ---------------- host ----------------

extern "C" void kernel_launch(void* const* d_in, const int* in_sizes, int n_in,
                              void* d_out, int out_size, void* d_ws, size_t ws_size,
                              hipStream_t stream) {
    const float* x  = (const float*)d_in[0];
    const float* W0 = (const float*)d_in[1];
    const float* b0 = (const float*)d_in[2];
    const float* W1 = (const float*)d_in[3];
    const float* b1 = (const float*)d_in[4];
    const float* W2 = (const float*)d_in[5];
    const float* b2 = (const float*)d_in[6];

    const int Bz = 4096;  // batch

    char* ws = (char*)d_ws;
    size_t off = 0;
    auto alloc = [&](size_t bytes) -> char* {
        char* p = ws + off;
        off += (bytes + 255) & ~(size_t)255;
        return p;
    };

    float* r1f = (float*)alloc((size_t)Bz * 2048 * 4);
    float* r2f = (float*)alloc((size_t)Bz * 2048 * 4);
    u16*   r1b = (u16*)  alloc((size_t)Bz * 2048 * 2);   // blocked
    u16*   r2b = (u16*)  alloc((size_t)Bz * 2048 * 2);   // blocked
    u16*   r3b = (u16*)  alloc((size_t)Bz * 512 * 2);    // blocked
    u16*   e0b = (u16*)  alloc((size_t)Bz * 1024 * 2);   // blocked
    u16*   e1b = (u16*)  alloc((size_t)Bz * 2048 * 2);   // blocked
    u16*   e2b = (u16*)  alloc((size_t)Bz * 2048 * 2);   // blocked
    u16*   xb  = (u16*)  alloc((size_t)Bz * 1024 * 2);   // blocked
    u16*   W0b = (u16*)  alloc((size_t)2048 * 1024 * 2); // blocked
    u16*   W0t = (u16*)  alloc((size_t)1024 * 2048 * 2); // blocked
    u16*   W1b = (u16*)  alloc((size_t)2048 * 2048 * 2); // blocked
    u16*   W1t = (u16*)  alloc((size_t)2048 * 2048 * 2); // blocked
    u16*   W2b = (u16*)  alloc((size_t)512 * 2048 * 2);  // blocked
    u16*   W2t = (u16*)  alloc((size_t)2048 * 512 * 2);  // blocked
    u16*   tmp = (u16*)  alloc((size_t)2048 * 2048 * 2); // row-major scratch

    float* r3f    = (float*)d_out;            // 4096 x 512
    float* errAcc = ((float*)d_out) + (size_t)Bz * 512;

    auto blkify = [&](const u16* s, u16* d, int M, int K) {
        blockify<<<(M / 128) * (K / 32), 256, 0, stream>>>(s, d, K);
    };

    // conversions: cvt/transpose to row-major tmp, then blockify (sequential on stream)
    cvt_bf16<<<(Bz * 1024 / 4) / 256, 256, 0, stream>>>(x, tmp, Bz * 1024 / 4);
    blkify(tmp, xb, Bz, 1024);
    cvt_bf16<<<(2048 * 1024 / 4) / 256, 256, 0, stream>>>(W0, tmp, 2048 * 1024 / 4);
    blkify(tmp, W0b, 2048, 1024);
    cvt_bf16<<<(2048 * 2048 / 4) / 256, 256, 0, stream>>>(W1, tmp, 2048 * 2048 / 4);
    blkify(tmp, W1b, 2048, 2048);
    cvt_bf16<<<(512 * 2048 / 4) / 256, 256, 0, stream>>>(W2, tmp, 512 * 2048 / 4);
    blkify(tmp, W2b, 512, 2048);
    transpose_cvt<<<dim3(1024 / 32, 2048 / 32), 256, 0, stream>>>(W0, tmp, 2048, 1024);
    blkify(tmp, W0t, 1024, 2048);
    transpose_cvt<<<dim3(2048 / 32, 2048 / 32), 256, 0, stream>>>(W1, tmp, 2048, 2048);
    blkify(tmp, W1t, 2048, 2048);
    transpose_cvt<<<dim3(2048 / 32, 512 / 32),  256, 0, stream>>>(W2, tmp, 512, 2048);
    blkify(tmp, W2t, 2048, 512);

    hipMemsetAsync(errAcc, 0, 4, stream);

    auto mkseg = [&](const u16* A, const u16* B, int K, int N,
                     const float* rsrc, const float* bias, const u16* esub,
                     float* outf, u16* outbf, int mode, int accum, int blkStart) {
        Seg s;
        s.A = A; s.B = B; s.rsrc = rsrc; s.bias = bias; s.esub = esub;
        s.outf = outf; s.outbf = outbf;
        s.K = K; s.N = N; s.blkStart = blkStart;
        s.mode = mode; s.accum = accum;
        return s;
    };
    auto nblk = [&](int N) { return (N / 128) * (Bz / 128); };

    auto launch1 = [&](Seg s0) {
        Phase ph;
        int b0 = nblk(s0.N);
        ph.seg[0] = s0; ph.seg[1] = s0; ph.seg[2] = s0;
        ph.bEnd0 = b0; ph.bEnd1 = b0;
        pc_phase<<<b0, 256, 0, stream>>>(ph, errAcc);
    };
    auto launch3 = [&](Seg s0, Seg s1, Seg s2) {
        Phase ph;
        int b0 = nblk(s0.N), b1 = nblk(s1.N), b2 = nblk(s2.N);
        s1.blkStart = b0; s2.blkStart = b0 + b1;
        ph.seg[0] = s0; ph.seg[1] = s1; ph.seg[2] = s2;
        ph.bEnd0 = b0; ph.bEnd1 = b0 + b1;
        pc_phase<<<b0 + b1 + b2, 256, 0, stream>>>(ph, errAcc);
    };

    // forward init (sequential dependency)
    launch1(mkseg(xb,  W0b, 1024, 2048, nullptr, b0, nullptr, r1f, r1b, 0, 0, 0));
    launch1(mkseg(r1b, W1b, 2048, 2048, nullptr, b1, nullptr, r2f, r2b, 0, 0, 0));
    launch1(mkseg(r2b, W2b, 2048, 512,  nullptr, b2, nullptr, r3f, r3b, 0, 0, 0));

    // 20 relaxation steps: fused error phase, fused update phase
    for (int s = 0; s < 20; ++s) {
        int last = (s == 19) ? 1 : 0;
        // errors (independent)
        launch3(mkseg(r2b, W1t, 2048, 2048, r1f, nullptr, nullptr, nullptr, e1b, 1, 0, 0),
                mkseg(r1b, W0t, 2048, 1024, x,   nullptr, nullptr, nullptr, e0b, 1, 0, 0),
                mkseg(r3b, W2t, 512,  2048, r2f, nullptr, nullptr, nullptr, e2b, 1, 0, 0));
        // updates (independent)
        launch3(mkseg(e1b, W1b, 2048, 2048, r2f, nullptr, e2b, r2f, r2b, 2, 0, 0),
                mkseg(e2b, W2b, 2048, 512,  r3f, nullptr, nullptr, r3f, r3b, 3, last, 0),
                mkseg(e0b, W0b, 1024, 2048, r1f, nullptr, e1b, r1f, r1b, 2, 0, 0));
    }

    // final errors with 0.5*sum(e^2) accumulation (r3^2 added by last UPD3)
    launch3(mkseg(r2b, W1t, 2048, 2048, r1f, nullptr, nullptr, nullptr, e1b, 1, 1, 0),
            mkseg(r1b, W0t, 2048, 1024, x,   nullptr, nullptr, nullptr, e0b, 1, 1, 0),
            mkseg(r3b, W2t, 512,  2048, r2f, nullptr, nullptr, nullptr, e2b, 1, 1, 0));
}

// Round 11
// 4096.697 us; speedup vs baseline: 3.6543x; 1.0023x over previous
//
#include <hip/hip_runtime.h>

typedef unsigned short u16;
typedef __bf16 bf16_t;
typedef bf16_t bf16x8 __attribute__((ext_vector_type(8)));
typedef u16 u16x8 __attribute__((ext_vector_type(8)));
typedef float f32x4 __attribute__((ext_vector_type(4)));

__device__ __forceinline__ u16 f2bf(float f) {
    unsigned u = __builtin_bit_cast(unsigned, f);
    u += 0x7fffu + ((u >> 16) & 1u);   // RNE
    return (u16)(u >> 16);
}
__device__ __forceinline__ float bf2f(u16 h) {
    unsigned u = ((unsigned)h) << 16;
    return __builtin_bit_cast(float, u);
}
__device__ __forceinline__ float fast_tanh(float x) {
    x = fminf(fmaxf(x, -20.f), 20.f);
    float e = __expf(2.f * x);
    return (e - 1.f) * __builtin_amdgcn_rcpf(e + 1.f);
}

__device__ __forceinline__ void gload_lds16(const void* g, void* l) {
    __builtin_amdgcn_global_load_lds((__attribute__((address_space(1))) void*)(g),
                                     (__attribute__((address_space(3))) void*)(l),
                                     16, 0, 0);
}

// Blocked layout: M x N (row-major logical) stored as 128x32 tiles, tile
// (m>>7, n>>5) contiguous 4096 elems; interior [kb=(n>>3)&3][row=m&127][n&7]
// == the LDS image the GEMM stages. A 128x128 output region of block (by,bx)
// is 4 consecutive tiles = 32 KB contiguous at ((by*(N>>5) + bx*4) * 4096).

// ---------------- conversion kernels ----------------

__global__ void cvt_bf16(const float* __restrict__ src, u16* __restrict__ dst, int n4) {
    int i = blockIdx.x * blockDim.x + threadIdx.x;
    if (i < n4) {
        float4 v = ((const float4*)src)[i];
        ushort4 o;
        o.x = f2bf(v.x); o.y = f2bf(v.y); o.z = f2bf(v.z); o.w = f2bf(v.w);
        ((ushort4*)dst)[i] = o;
    }
}

// W: R x C fp32  ->  WT: C x R bf16 (row-major)
__global__ void transpose_cvt(const float* __restrict__ W, u16* __restrict__ WT, int R, int C) {
    __shared__ float tile[32][33];
    int c0 = blockIdx.x * 32, r0 = blockIdx.y * 32;
    int tx = threadIdx.x & 31, ty = threadIdx.x >> 5;  // 32x8
#pragma unroll
    for (int i = 0; i < 32; i += 8)
        tile[ty + i][tx] = W[(size_t)(r0 + ty + i) * C + (c0 + tx)];
    __syncthreads();
#pragma unroll
    for (int i = 0; i < 32; i += 8)
        WT[(size_t)(c0 + ty + i) * R + (r0 + tx)] = f2bf(tile[tx][ty + i]);
}

// row-major bf16 (M x K) -> blocked layout. grid = (M/128)*(K/32), 256 thr.
__global__ void blockify(const u16* __restrict__ src, u16* __restrict__ dst, int K) {
    const int nk = K >> 5;
    const int rb = blockIdx.x / nk, cb = blockIdx.x % nk;
    const int t = threadIdx.x;
    const int kloc = (t & 7) * 4;
    u16* d = dst + (size_t)blockIdx.x * 4096 + ((kloc >> 3) << 10) + (kloc & 7);
    const u16* s = src + (size_t)(rb * 128) * K + cb * 32 + kloc;
#pragma unroll
    for (int p = 0; p < 4; ++p) {
        int row = (t >> 3) + p * 32;
        *(ushort4*)(d + row * 8) = *(const ushort4*)(s + (size_t)row * K);
    }
}

// ---------------- segmented fused NT GEMM phase ----------------
// C[m,n] = sum_k A[m,k]*B[n,k]; A,B blocked bf16. bf16 blocked state is the
// MASTER for r1/r2/e*; r3 keeps an f32 row-major master (d_out).
// mode 0 (FWD):  v = tanh(C + bias[n]);                       -> outbf [+outf]
// mode 1 (ERR):  v = rsrcb - tanh(C);                         -> outbf  (+0.5v^2)
// mode 2 (UPD):  v = rsrcb + 0.1*(C - esub);                  -> outbf (in-place ok)
// mode 3 (UPD3): v = 0.9*rsrcf + 0.1*C;                       -> outf, outbf (+0.5v^2)
// Epilogue does all blocked-tensor I/O via LDS quarter-images (coalesced).

struct Seg {
    const u16* A; const u16* B;
    const u16* rsrcb;          // blocked bf16 (modes 1,2)
    const float* rsrcf;        // f32 row-major (mode 3)
    const float* bias;         // f32 (mode 0)
    const u16* esub;           // blocked bf16 (mode 2)
    float* outf;               // f32 row-major (modes 0(r3),3)
    u16* outbf;                // blocked bf16 (all modes)
    int K, N, blkStart, mode, accum;
};
struct Phase {
    Seg seg[3];
    int bEnd0, bEnd1;
};

__global__ __launch_bounds__(256, 4) void pc_phase(Phase ph, float* __restrict__ errAcc) {
    __shared__ u16 As[4096];   // K-loop: A image; epilogue: imgA (8 KB)
    __shared__ u16 Bs[4096];   // K-loop: B image; epilogue: imgB (8 KB)
    __shared__ float red[4];

    const int bid = blockIdx.x;
    const int segi = (bid >= ph.bEnd0 ? 1 : 0) + (bid >= ph.bEnd1 ? 1 : 0);

    const int local = bid - ph.seg[segi].blkStart;
    const int bx = local >> 5;        // N-tile (weight-major grouping)
    const int by = local & 31;        // M-tile (batch rows)
    const int K = ph.seg[segi].K;

    const int tid  = threadIdx.x;
    const int wave = tid >> 6, lane = tid & 63;
    const int q    = lane >> 4, ln = lane & 15;
    const int wrow = (wave >> 1) * 64, wcol = (wave & 1) * 64;

    const int nk = K >> 5;
    const u16* tA = ph.seg[segi].A + (size_t)by * nk * 4096 + wave * 1024 + lane * 8;
    const u16* tB = ph.seg[segi].B + (size_t)bx * nk * 4096 + wave * 1024 + lane * 8;
    u16* lA0 = &As[wave * 1024];
    u16* lA1 = &As[wave * 1024 + 512];
    u16* lB0 = &Bs[wave * 1024];
    u16* lB1 = &Bs[wave * 1024 + 512];

    f32x4 acc[4][4];
#pragma unroll
    for (int i = 0; i < 4; ++i)
#pragma unroll
        for (int j = 0; j < 4; ++j)
            acc[i][j] = (f32x4){0.f, 0.f, 0.f, 0.f};

    const u16* asrd = &As[q * 1024 + (wrow + ln) * 8];
    const u16* bsrd = &Bs[q * 1024 + (wcol + ln) * 8];

    for (int k = 0; k < nk; ++k) {
        const size_t kb = (size_t)k * 4096;
        gload_lds16(tA + kb, lA0);
        gload_lds16(tA + kb + 512, lA1);
        gload_lds16(tB + kb, lB0);
        gload_lds16(tB + kb + 512, lB1);
        __syncthreads();

        bf16x8 a[4], b[4];
#pragma unroll
        for (int mt = 0; mt < 4; ++mt)
            a[mt] = __builtin_bit_cast(bf16x8, *(const u16x8*)&asrd[mt * 128]);
#pragma unroll
        for (int nt = 0; nt < 4; ++nt)
            b[nt] = __builtin_bit_cast(bf16x8, *(const u16x8*)&bsrd[nt * 128]);
#pragma unroll
        for (int mt = 0; mt < 4; ++mt)
#pragma unroll
            for (int nt = 0; nt < 4; ++nt)
                acc[mt][nt] = __builtin_amdgcn_mfma_f32_16x16x32_bf16(
                    a[mt], b[nt], acc[mt][nt], 0, 0, 0);
        __syncthreads();
    }

    // ---------------- epilogue ----------------
    const int N = ph.seg[segi].N;
    const int mode = ph.seg[segi].mode;
    const int accum = ph.seg[segi].accum;
    const u16* rsrcb = ph.seg[segi].rsrcb;
    const float* rsrcf = ph.seg[segi].rsrcf;
    const float* bias = ph.seg[segi].bias;
    const u16* esub = ph.seg[segi].esub;
    float* outf = ph.seg[segi].outf;
    u16* outbf = ph.seg[segi].outbf;

    const int rowA0 = by * 128;
    const int rowB0 = bx * 128;
    const size_t regionOff = ((size_t)by * (N >> 5) + bx * 4) * 4096;
    const u16* rsrcR = rsrcb ? rsrcb + regionOff : nullptr;
    const u16* esubR = esub ? esub + regionOff : nullptr;
    u16* outR = outbf + regionOff;

    // quarter image copy: img[o] <-> region[(chunk>>2)*4096 + (chunk&3)*1024
    //                                      + qq*256 + (o&255)], chunk = o>>8
    const int o0 = tid * 16;
    const int ch = o0 >> 8;
    const size_t gq = (size_t)(ch >> 2) * 4096 + (size_t)(ch & 3) * 1024 + (o0 & 255);

    float lsum = 0.f;
    const int myHalf = wave >> 1;            // which pair of quarters this wave owns

#pragma unroll
    for (int qq = 0; qq < 4; ++qq) {
        const size_t g = gq + qq * 256;
        if (mode == 1 || mode == 2) {
            *(u16x8*)(As + o0)     = *(const u16x8*)(rsrcR + g);
            *(u16x8*)(As + o0 + 8) = *(const u16x8*)(rsrcR + g + 8);
        }
        if (mode == 2) {
            *(u16x8*)(Bs + o0)     = *(const u16x8*)(esubR + g);
            *(u16x8*)(Bs + o0 + 8) = *(const u16x8*)(esubR + g + 8);
        }
        __syncthreads();

        if ((qq >> 1) == myHalf) {
            const int mtlo = (qq & 1) * 2;
#pragma unroll
            for (int mi = 0; mi < 2; ++mi) {
                const int mt = mtlo + mi;
#pragma unroll
                for (int r = 0; r < 4; ++r) {
                    const int rl = mi * 16 + q * 4 + r;      // row within quarter
                    const int m = rowA0 + wrow + mt * 16 + q * 4 + r;
#pragma unroll
                    for (int nt = 0; nt < 4; ++nt) {
                        const int nrel = wcol + nt * 16 + ln;
                        const int o = (nrel >> 3) * 256 + rl * 8 + (nrel & 7);
                        const float c = acc[mt][nt][r];
                        float v;
                        if (mode == 0) {
                            v = fast_tanh(c + bias[rowB0 + nrel]);
                            if (outf) outf[(size_t)m * N + rowB0 + nrel] = v;
                        } else if (mode == 1) {
                            v = bf2f(As[o]) - fast_tanh(c);
                            if (accum) lsum += v * v;
                        } else if (mode == 2) {
                            v = bf2f(As[o]) + 0.1f * (c - bf2f(Bs[o]));
                        } else {
                            const size_t idx = (size_t)m * N + rowB0 + nrel;
                            v = 0.9f * rsrcf[idx] + 0.1f * c;
                            outf[idx] = v;
                            if (accum) lsum += v * v;
                        }
                        As[o] = f2bf(v);
                    }
                }
            }
        }
        __syncthreads();
        // coalesced copy-out of the quarter
        *(u16x8*)(outR + g)     = *(const u16x8*)(As + o0);
        *(u16x8*)(outR + g + 8) = *(const u16x8*)(As + o0 + 8);
        __syncthreads();   // before next quarter overwrites the images
    }

    if (accum) {
        lsum *= 0.5f;
#pragma unroll
        for (int o = 32; o > 0; o >>= 1) lsum += __shfl_down(lsum, o);
        if (lane == 0) red[wave] = lsum;
        __syncthreads();
        if (tid == 0) atomicAdd(errAcc, red[0] + red[1] + red[2] + red[3]);
    }
}

// ---------------- host ----------------

extern "C" void kernel_launch(void* const* d_in, const int* in_sizes, int n_in,
                              void* d_out, int out_size, void* d_ws, size_t ws_size,
                              hipStream_t stream) {
    const float* x  = (const float*)d_in[0];
    const float* W0 = (const float*)d_in[1];
    const float* b0 = (const float*)d_in[2];
    const float* W1 = (const float*)d_in[3];
    const float* b1 = (const float*)d_in[4];
    const float* W2 = (const float*)d_in[5];
    const float* b2 = (const float*)d_in[6];

    const int Bz = 4096;  // batch

    char* ws = (char*)d_ws;
    size_t off = 0;
    auto alloc = [&](size_t bytes) -> char* {
        char* p = ws + off;
        off += (bytes + 255) & ~(size_t)255;
        return p;
    };

    u16*   r1b = (u16*)  alloc((size_t)Bz * 2048 * 2);   // blocked, MASTER r1
    u16*   r2b = (u16*)  alloc((size_t)Bz * 2048 * 2);   // blocked, MASTER r2
    u16*   r3b = (u16*)  alloc((size_t)Bz * 512 * 2);    // blocked
    u16*   e0b = (u16*)  alloc((size_t)Bz * 1024 * 2);   // blocked
    u16*   e1b = (u16*)  alloc((size_t)Bz * 2048 * 2);   // blocked
    u16*   e2b = (u16*)  alloc((size_t)Bz * 2048 * 2);   // blocked
    u16*   xb  = (u16*)  alloc((size_t)Bz * 1024 * 2);   // blocked
    u16*   W0b = (u16*)  alloc((size_t)2048 * 1024 * 2);
    u16*   W0t = (u16*)  alloc((size_t)1024 * 2048 * 2);
    u16*   W1b = (u16*)  alloc((size_t)2048 * 2048 * 2);
    u16*   W1t = (u16*)  alloc((size_t)2048 * 2048 * 2);
    u16*   W2b = (u16*)  alloc((size_t)512 * 2048 * 2);
    u16*   W2t = (u16*)  alloc((size_t)2048 * 512 * 2);
    u16*   tmp = (u16*)  alloc((size_t)2048 * 2048 * 2); // row-major scratch

    float* r3f    = (float*)d_out;            // 4096 x 512, f32 MASTER r3
    float* errAcc = ((float*)d_out) + (size_t)Bz * 512;

    auto blkify = [&](const u16* s, u16* d, int M, int K) {
        blockify<<<(M / 128) * (K / 32), 256, 0, stream>>>(s, d, K);
    };

    cvt_bf16<<<(Bz * 1024 / 4) / 256, 256, 0, stream>>>(x, tmp, Bz * 1024 / 4);
    blkify(tmp, xb, Bz, 1024);
    cvt_bf16<<<(2048 * 1024 / 4) / 256, 256, 0, stream>>>(W0, tmp, 2048 * 1024 / 4);
    blkify(tmp, W0b, 2048, 1024);
    cvt_bf16<<<(2048 * 2048 / 4) / 256, 256, 0, stream>>>(W1, tmp, 2048 * 2048 / 4);
    blkify(tmp, W1b, 2048, 2048);
    cvt_bf16<<<(512 * 2048 / 4) / 256, 256, 0, stream>>>(W2, tmp, 512 * 2048 / 4);
    blkify(tmp, W2b, 512, 2048);
    transpose_cvt<<<dim3(1024 / 32, 2048 / 32), 256, 0, stream>>>(W0, tmp, 2048, 1024);
    blkify(tmp, W0t, 1024, 2048);
    transpose_cvt<<<dim3(2048 / 32, 2048 / 32), 256, 0, stream>>>(W1, tmp, 2048, 2048);
    blkify(tmp, W1t, 2048, 2048);
    transpose_cvt<<<dim3(2048 / 32, 512 / 32),  256, 0, stream>>>(W2, tmp, 512, 2048);
    blkify(tmp, W2t, 2048, 512);

    hipMemsetAsync(errAcc, 0, 4, stream);

    auto mkseg = [&](const u16* A, const u16* B, int K, int N,
                     const u16* rsrcb, const float* rsrcf, const float* bias,
                     const u16* esub, float* outf, u16* outbf,
                     int mode, int accum) {
        Seg s;
        s.A = A; s.B = B; s.rsrcb = rsrcb; s.rsrcf = rsrcf; s.bias = bias;
        s.esub = esub; s.outf = outf; s.outbf = outbf;
        s.K = K; s.N = N; s.blkStart = 0; s.mode = mode; s.accum = accum;
        return s;
    };
    auto nblk = [&](int N) { return (N / 128) * (Bz / 128); };

    auto launch1 = [&](Seg s0) {
        Phase ph;
        int b0 = nblk(s0.N);
        ph.seg[0] = s0; ph.seg[1] = s0; ph.seg[2] = s0;
        ph.bEnd0 = b0; ph.bEnd1 = b0;
        pc_phase<<<b0, 256, 0, stream>>>(ph, errAcc);
    };
    auto launch3 = [&](Seg s0, Seg s1, Seg s2) {
        Phase ph;
        int b0 = nblk(s0.N), b1 = nblk(s1.N), b2 = nblk(s2.N);
        s1.blkStart = b0; s2.blkStart = b0 + b1;
        ph.seg[0] = s0; ph.seg[1] = s1; ph.seg[2] = s2;
        ph.bEnd0 = b0; ph.bEnd1 = b0 + b1;
        pc_phase<<<b0 + b1 + b2, 256, 0, stream>>>(ph, errAcc);
    };

    // forward init (sequential dependency)
    launch1(mkseg(xb,  W0b, 1024, 2048, nullptr, nullptr, b0, nullptr, nullptr, r1b, 0, 0));
    launch1(mkseg(r1b, W1b, 2048, 2048, nullptr, nullptr, b1, nullptr, nullptr, r2b, 0, 0));
    launch1(mkseg(r2b, W2b, 2048, 512,  nullptr, nullptr, b2, nullptr, r3f,     r3b, 0, 0));

    // 20 relaxation steps
    for (int s = 0; s < 20; ++s) {
        int last = (s == 19) ? 1 : 0;
        // errors (independent; read old state)
        launch3(mkseg(r2b, W1t, 2048, 2048, r1b, nullptr, nullptr, nullptr, nullptr, e1b, 1, 0),
                mkseg(r1b, W0t, 2048, 1024, xb,  nullptr, nullptr, nullptr, nullptr, e0b, 1, 0),
                mkseg(r3b, W2t, 512,  2048, r2b, nullptr, nullptr, nullptr, nullptr, e2b, 1, 0));
        // updates (independent; in-place on bf16 masters)
        launch3(mkseg(e1b, W1b, 2048, 2048, r2b, nullptr, nullptr, e2b, nullptr, r2b, 2, 0),
                mkseg(e2b, W2b, 2048, 512,  nullptr, r3f, nullptr, nullptr, r3f,  r3b, 3, last),
                mkseg(e0b, W0b, 1024, 2048, r1b, nullptr, nullptr, e1b, nullptr, r1b, 2, 0));
    }

    // final errors with 0.5*sum(e^2) accumulation (r3^2 added by last UPD3)
    launch3(mkseg(r2b, W1t, 2048, 2048, r1b, nullptr, nullptr, nullptr, nullptr, e1b, 1, 1),
            mkseg(r1b, W0t, 2048, 1024, xb,  nullptr, nullptr, nullptr, nullptr, e0b, 1, 1),
            mkseg(r3b, W2t, 512,  2048, r2b, nullptr, nullptr, nullptr, nullptr, e2b, 1, 1));
}

// Round 12
// 3951.314 us; speedup vs baseline: 3.7888x; 1.0368x over previous
//
#include <hip/hip_runtime.h>

typedef unsigned short u16;
typedef __bf16 bf16_t;
typedef bf16_t bf16x8 __attribute__((ext_vector_type(8)));
typedef u16 u16x8 __attribute__((ext_vector_type(8)));
typedef float f32x4 __attribute__((ext_vector_type(4)));

__device__ __forceinline__ u16 f2bf(float f) {
    unsigned u = __builtin_bit_cast(unsigned, f);
    u += 0x7fffu + ((u >> 16) & 1u);   // RNE
    return (u16)(u >> 16);
}
__device__ __forceinline__ float bf2f(u16 h) {
    unsigned u = ((unsigned)h) << 16;
    return __builtin_bit_cast(float, u);
}
__device__ __forceinline__ float fast_tanh(float x) {
    x = fminf(fmaxf(x, -20.f), 20.f);
    float e = __expf(2.f * x);
    return (e - 1.f) * __builtin_amdgcn_rcpf(e + 1.f);
}

__device__ __forceinline__ void gload_lds16(const void* g, void* l) {
    __builtin_amdgcn_global_load_lds((__attribute__((address_space(1))) void*)(g),
                                     (__attribute__((address_space(3))) void*)(l),
                                     16, 0, 0);
}

// s_waitcnt immediates (validated on this harness in R8): vmcnt low bits [3:0],
// all other count fields set to "no wait".
#define WAITCNT_VM4 0x3F74
#define WAITCNT_VM0 0x3F70

// Blocked layout: M x N stored as 128x32 tiles, tile (m>>7,n>>5) contiguous
// 4096 elems; interior [kb=(n>>3)&3][row=m&127][n&7] == the LDS staging image.
// A 128x128 region of block (by,bx) = 4 consecutive tiles = 32 KB contiguous.

// ---------------- conversion kernels ----------------

__global__ void cvt_bf16(const float* __restrict__ src, u16* __restrict__ dst, int n4) {
    int i = blockIdx.x * blockDim.x + threadIdx.x;
    if (i < n4) {
        float4 v = ((const float4*)src)[i];
        ushort4 o;
        o.x = f2bf(v.x); o.y = f2bf(v.y); o.z = f2bf(v.z); o.w = f2bf(v.w);
        ((ushort4*)dst)[i] = o;
    }
}

// W: R x C fp32  ->  WT: C x R bf16 (row-major)
__global__ void transpose_cvt(const float* __restrict__ W, u16* __restrict__ WT, int R, int C) {
    __shared__ float tile[32][33];
    int c0 = blockIdx.x * 32, r0 = blockIdx.y * 32;
    int tx = threadIdx.x & 31, ty = threadIdx.x >> 5;  // 32x8
#pragma unroll
    for (int i = 0; i < 32; i += 8)
        tile[ty + i][tx] = W[(size_t)(r0 + ty + i) * C + (c0 + tx)];
    __syncthreads();
#pragma unroll
    for (int i = 0; i < 32; i += 8)
        WT[(size_t)(c0 + ty + i) * R + (r0 + tx)] = f2bf(tile[tx][ty + i]);
}

// row-major bf16 (M x K) -> blocked layout. grid = (M/128)*(K/32), 256 thr.
__global__ void blockify(const u16* __restrict__ src, u16* __restrict__ dst, int K) {
    const int nk = K >> 5;
    const int rb = blockIdx.x / nk, cb = blockIdx.x % nk;
    const int t = threadIdx.x;
    const int kloc = (t & 7) * 4;
    u16* d = dst + (size_t)blockIdx.x * 4096 + ((kloc >> 3) << 10) + (kloc & 7);
    const u16* s = src + (size_t)(rb * 128) * K + cb * 32 + kloc;
#pragma unroll
    for (int p = 0; p < 4; ++p) {
        int row = (t >> 3) + p * 32;
        *(ushort4*)(d + row * 8) = *(const ushort4*)(s + (size_t)row * K);
    }
}

// ---------------- segmented fused NT GEMM phase ----------------
// Manual software pipeline: double-buffered LDS, prologue stages tiles 0,1;
// per iter: s_waitcnt vmcnt(4) (own tile-k loads landed, k+1 in flight) ->
// raw s_barrier -> MFMA on tile k -> raw s_barrier (buffer reuse; NO drain) ->
// issue tile k+2. Hides one full iteration of load latency vs __syncthreads'
// implicit vmcnt(0) drain.
// mode 0 (FWD):  v = tanh(C + bias[n]);            -> outbf [+outf]
// mode 1 (ERR):  v = rsrcb - tanh(C);              -> outbf  (+0.5v^2)
// mode 2 (UPD):  v = rsrcb + 0.1*(C - esub);       -> outbf (in-place ok)
// mode 3 (UPD3): v = 0.9*rsrcf + 0.1*C;            -> outf, outbf (+0.5v^2)

struct Seg {
    const u16* A; const u16* B;
    const u16* rsrcb;          // blocked bf16 (modes 1,2)
    const float* rsrcf;        // f32 row-major (mode 3)
    const float* bias;         // f32 (mode 0)
    const u16* esub;           // blocked bf16 (mode 2)
    float* outf;               // f32 row-major (modes 0(r3),3)
    u16* outbf;                // blocked bf16 (all modes)
    int K, N, blkStart, mode, accum;
};
struct Phase {
    Seg seg[3];
    int bEnd0, bEnd1;
};

__global__ __launch_bounds__(256, 4) void pc_phase(Phase ph, float* __restrict__ errAcc) {
    __shared__ u16 As[2][4096];   // double-buffered staging; epilogue reuses As[0..] as images
    __shared__ u16 Bs[2][4096];
    __shared__ float red[4];

    const int bid = blockIdx.x;
    const int segi = (bid >= ph.bEnd0 ? 1 : 0) + (bid >= ph.bEnd1 ? 1 : 0);

    const int local = bid - ph.seg[segi].blkStart;
    const int bx = local >> 5;        // N-tile (weight-major grouping)
    const int by = local & 31;        // M-tile (batch rows)
    const int K = ph.seg[segi].K;

    const int tid  = threadIdx.x;
    const int wave = tid >> 6, lane = tid & 63;
    const int q    = lane >> 4, ln = lane & 15;
    const int wrow = (wave >> 1) * 64, wcol = (wave & 1) * 64;

    const int nk = K >> 5;
    const u16* tA = ph.seg[segi].A + (size_t)by * nk * 4096 + wave * 1024 + lane * 8;
    const u16* tB = ph.seg[segi].B + (size_t)bx * nk * 4096 + wave * 1024 + lane * 8;

    f32x4 acc[4][4];
#pragma unroll
    for (int i = 0; i < 4; ++i)
#pragma unroll
        for (int j = 0; j < 4; ++j)
            acc[i][j] = (f32x4){0.f, 0.f, 0.f, 0.f};

    auto issueTile = [&](int k, int buf) {
        const size_t kb = (size_t)k * 4096;
        gload_lds16(tA + kb,       &As[buf][wave * 1024]);
        gload_lds16(tA + kb + 512, &As[buf][wave * 1024 + 512]);
        gload_lds16(tB + kb,       &Bs[buf][wave * 1024]);
        gload_lds16(tB + kb + 512, &Bs[buf][wave * 1024 + 512]);
    };

    // prologue: stage tiles 0 and 1
    issueTile(0, 0);
    if (nk > 1) issueTile(1, 1);

    const int ardo = q * 1024 + (wrow + ln) * 8;
    const int brdo = q * 1024 + (wcol + ln) * 8;

    for (int k = 0; k < nk; ++k) {
        asm volatile("" ::: "memory");
        if (k + 1 < nk) __builtin_amdgcn_s_waitcnt(WAITCNT_VM4);  // tile k landed
        else            __builtin_amdgcn_s_waitcnt(WAITCNT_VM0);
        __builtin_amdgcn_s_barrier();      // all waves' tile-k data visible
        asm volatile("" ::: "memory");

        const u16* as = &As[k & 1][ardo];
        const u16* bs = &Bs[k & 1][brdo];
        bf16x8 a[4], b[4];
#pragma unroll
        for (int mt = 0; mt < 4; ++mt)
            a[mt] = __builtin_bit_cast(bf16x8, *(const u16x8*)&as[mt * 128]);
#pragma unroll
        for (int nt = 0; nt < 4; ++nt)
            b[nt] = __builtin_bit_cast(bf16x8, *(const u16x8*)&bs[nt * 128]);
#pragma unroll
        for (int mt = 0; mt < 4; ++mt)
#pragma unroll
            for (int nt = 0; nt < 4; ++nt)
                acc[mt][nt] = __builtin_amdgcn_mfma_f32_16x16x32_bf16(
                    a[mt], b[nt], acc[mt][nt], 0, 0, 0);

        asm volatile("" ::: "memory");
        __builtin_amdgcn_s_barrier();      // all waves done reading buf[k&1]
        asm volatile("" ::: "memory");
        if (k + 2 < nk) issueTile(k + 2, k & 1);
    }

    // ---------------- epilogue ----------------
    const int N = ph.seg[segi].N;
    const int mode = ph.seg[segi].mode;
    const int accum = ph.seg[segi].accum;
    const u16* rsrcb = ph.seg[segi].rsrcb;
    const float* rsrcf = ph.seg[segi].rsrcf;
    const float* bias = ph.seg[segi].bias;
    const u16* esub = ph.seg[segi].esub;
    float* outf = ph.seg[segi].outf;
    u16* outbf = ph.seg[segi].outbf;

    const int rowA0 = by * 128;
    const int rowB0 = bx * 128;
    const size_t regionOff = ((size_t)by * (N >> 5) + bx * 4) * 4096;
    const u16* rsrcR = rsrcb ? rsrcb + regionOff : nullptr;
    const u16* esubR = esub ? esub + regionOff : nullptr;
    u16* outR = outbf + regionOff;

    u16* imgA = &As[0][0];   // 8 KB quarter image
    u16* imgB = &Bs[0][0];

    const int o0 = tid * 16;
    const int ch = o0 >> 8;
    const size_t gq = (size_t)(ch >> 2) * 4096 + (size_t)(ch & 3) * 1024 + (o0 & 255);

    float lsum = 0.f;
    const int myHalf = wave >> 1;

#pragma unroll
    for (int qq = 0; qq < 4; ++qq) {
        const size_t g = gq + qq * 256;
        if (mode == 1 || mode == 2) {
            *(u16x8*)(imgA + o0)     = *(const u16x8*)(rsrcR + g);
            *(u16x8*)(imgA + o0 + 8) = *(const u16x8*)(rsrcR + g + 8);
        }
        if (mode == 2) {
            *(u16x8*)(imgB + o0)     = *(const u16x8*)(esubR + g);
            *(u16x8*)(imgB + o0 + 8) = *(const u16x8*)(esubR + g + 8);
        }
        __syncthreads();

        if ((qq >> 1) == myHalf) {
            const int mtlo = (qq & 1) * 2;
#pragma unroll
            for (int mi = 0; mi < 2; ++mi) {
                const int mt = mtlo + mi;
#pragma unroll
                for (int r = 0; r < 4; ++r) {
                    const int rl = mi * 16 + q * 4 + r;
                    const int m = rowA0 + wrow + mt * 16 + q * 4 + r;
#pragma unroll
                    for (int nt = 0; nt < 4; ++nt) {
                        const int nrel = wcol + nt * 16 + ln;
                        const int o = (nrel >> 3) * 256 + rl * 8 + (nrel & 7);
                        const float c = acc[mt][nt][r];
                        float v;
                        if (mode == 0) {
                            v = fast_tanh(c + bias[rowB0 + nrel]);
                            if (outf) outf[(size_t)m * N + rowB0 + nrel] = v;
                        } else if (mode == 1) {
                            v = bf2f(imgA[o]) - fast_tanh(c);
                            if (accum) lsum += v * v;
                        } else if (mode == 2) {
                            v = bf2f(imgA[o]) + 0.1f * (c - bf2f(imgB[o]));
                        } else {
                            const size_t idx = (size_t)m * N + rowB0 + nrel;
                            v = 0.9f * rsrcf[idx] + 0.1f * c;
                            outf[idx] = v;
                            if (accum) lsum += v * v;
                        }
                        imgA[o] = f2bf(v);
                    }
                }
            }
        }
        __syncthreads();
        *(u16x8*)(outR + g)     = *(const u16x8*)(imgA + o0);
        *(u16x8*)(outR + g + 8) = *(const u16x8*)(imgA + o0 + 8);
        __syncthreads();
    }

    if (accum) {
        lsum *= 0.5f;
#pragma unroll
        for (int o = 32; o > 0; o >>= 1) lsum += __shfl_down(lsum, o);
        if (lane == 0) red[wave] = lsum;
        __syncthreads();
        if (tid == 0) atomicAdd(errAcc, red[0] + red[1] + red[2] + red[3]);
    }
}

// ---------------- host ----------------

extern "C" void kernel_launch(void* const* d_in, const int* in_sizes, int n_in,
                              void* d_out, int out_size, void* d_ws, size_t ws_size,
                              hipStream_t stream) {
    const float* x  = (const float*)d_in[0];
    const float* W0 = (const float*)d_in[1];
    const float* b0 = (const float*)d_in[2];
    const float* W1 = (const float*)d_in[3];
    const float* b1 = (const float*)d_in[4];
    const float* W2 = (const float*)d_in[5];
    const float* b2 = (const float*)d_in[6];

    const int Bz = 4096;  // batch

    char* ws = (char*)d_ws;
    size_t off = 0;
    auto alloc = [&](size_t bytes) -> char* {
        char* p = ws + off;
        off += (bytes + 255) & ~(size_t)255;
        return p;
    };

    u16*   r1b = (u16*)  alloc((size_t)Bz * 2048 * 2);   // blocked, MASTER r1
    u16*   r2b = (u16*)  alloc((size_t)Bz * 2048 * 2);   // blocked, MASTER r2
    u16*   r3b = (u16*)  alloc((size_t)Bz * 512 * 2);    // blocked
    u16*   e0b = (u16*)  alloc((size_t)Bz * 1024 * 2);   // blocked
    u16*   e1b = (u16*)  alloc((size_t)Bz * 2048 * 2);   // blocked
    u16*   e2b = (u16*)  alloc((size_t)Bz * 2048 * 2);   // blocked
    u16*   xb  = (u16*)  alloc((size_t)Bz * 1024 * 2);   // blocked
    u16*   W0b = (u16*)  alloc((size_t)2048 * 1024 * 2);
    u16*   W0t = (u16*)  alloc((size_t)1024 * 2048 * 2);
    u16*   W1b = (u16*)  alloc((size_t)2048 * 2048 * 2);
    u16*   W1t = (u16*)  alloc((size_t)2048 * 2048 * 2);
    u16*   W2b = (u16*)  alloc((size_t)512 * 2048 * 2);
    u16*   W2t = (u16*)  alloc((size_t)2048 * 512 * 2);
    u16*   tmp = (u16*)  alloc((size_t)2048 * 2048 * 2); // row-major scratch

    float* r3f    = (float*)d_out;            // 4096 x 512, f32 MASTER r3
    float* errAcc = ((float*)d_out) + (size_t)Bz * 512;

    auto blkify = [&](const u16* s, u16* d, int M, int K) {
        blockify<<<(M / 128) * (K / 32), 256, 0, stream>>>(s, d, K);
    };

    cvt_bf16<<<(Bz * 1024 / 4) / 256, 256, 0, stream>>>(x, tmp, Bz * 1024 / 4);
    blkify(tmp, xb, Bz, 1024);
    cvt_bf16<<<(2048 * 1024 / 4) / 256, 256, 0, stream>>>(W0, tmp, 2048 * 1024 / 4);
    blkify(tmp, W0b, 2048, 1024);
    cvt_bf16<<<(2048 * 2048 / 4) / 256, 256, 0, stream>>>(W1, tmp, 2048 * 2048 / 4);
    blkify(tmp, W1b, 2048, 2048);
    cvt_bf16<<<(512 * 2048 / 4) / 256, 256, 0, stream>>>(W2, tmp, 512 * 2048 / 4);
    blkify(tmp, W2b, 512, 2048);
    transpose_cvt<<<dim3(1024 / 32, 2048 / 32), 256, 0, stream>>>(W0, tmp, 2048, 1024);
    blkify(tmp, W0t, 1024, 2048);
    transpose_cvt<<<dim3(2048 / 32, 2048 / 32), 256, 0, stream>>>(W1, tmp, 2048, 2048);
    blkify(tmp, W1t, 2048, 2048);
    transpose_cvt<<<dim3(2048 / 32, 512 / 32),  256, 0, stream>>>(W2, tmp, 512, 2048);
    blkify(tmp, W2t, 2048, 512);

    hipMemsetAsync(errAcc, 0, 4, stream);

    auto mkseg = [&](const u16* A, const u16* B, int K, int N,
                     const u16* rsrcb, const float* rsrcf, const float* bias,
                     const u16* esub, float* outf, u16* outbf,
                     int mode, int accum) {
        Seg s;
        s.A = A; s.B = B; s.rsrcb = rsrcb; s.rsrcf = rsrcf; s.bias = bias;
        s.esub = esub; s.outf = outf; s.outbf = outbf;
        s.K = K; s.N = N; s.blkStart = 0; s.mode = mode; s.accum = accum;
        return s;
    };
    auto nblk = [&](int N) { return (N / 128) * (Bz / 128); };

    auto launch1 = [&](Seg s0) {
        Phase ph;
        int b0 = nblk(s0.N);
        ph.seg[0] = s0; ph.seg[1] = s0; ph.seg[2] = s0;
        ph.bEnd0 = b0; ph.bEnd1 = b0;
        pc_phase<<<b0, 256, 0, stream>>>(ph, errAcc);
    };
    auto launch3 = [&](Seg s0, Seg s1, Seg s2) {
        Phase ph;
        int b0 = nblk(s0.N), b1 = nblk(s1.N), b2 = nblk(s2.N);
        s1.blkStart = b0; s2.blkStart = b0 + b1;
        ph.seg[0] = s0; ph.seg[1] = s1; ph.seg[2] = s2;
        ph.bEnd0 = b0; ph.bEnd1 = b0 + b1;
        pc_phase<<<b0 + b1 + b2, 256, 0, stream>>>(ph, errAcc);
    };

    // forward init (sequential dependency)
    launch1(mkseg(xb,  W0b, 1024, 2048, nullptr, nullptr, b0, nullptr, nullptr, r1b, 0, 0));
    launch1(mkseg(r1b, W1b, 2048, 2048, nullptr, nullptr, b1, nullptr, nullptr, r2b, 0, 0));
    launch1(mkseg(r2b, W2b, 2048, 512,  nullptr, nullptr, b2, nullptr, r3f,     r3b, 0, 0));

    // 20 relaxation steps
    for (int s = 0; s < 20; ++s) {
        int last = (s == 19) ? 1 : 0;
        // errors (independent; read old state)
        launch3(mkseg(r2b, W1t, 2048, 2048, r1b, nullptr, nullptr, nullptr, nullptr, e1b, 1, 0),
                mkseg(r1b, W0t, 2048, 1024, xb,  nullptr, nullptr, nullptr, nullptr, e0b, 1, 0),
                mkseg(r3b, W2t, 512,  2048, r2b, nullptr, nullptr, nullptr, nullptr, e2b, 1, 0));
        // updates (independent; in-place on bf16 masters)
        launch3(mkseg(e1b, W1b, 2048, 2048, r2b, nullptr, nullptr, e2b, nullptr, r2b, 2, 0),
                mkseg(e2b, W2b, 2048, 512,  nullptr, r3f, nullptr, nullptr, r3f,  r3b, 3, last),
                mkseg(e0b, W0b, 1024, 2048, r1b, nullptr, nullptr, e1b, nullptr, r1b, 2, 0));
    }

    // final errors with 0.5*sum(e^2) accumulation (r3^2 added by last UPD3)
    launch3(mkseg(r2b, W1t, 2048, 2048, r1b, nullptr, nullptr, nullptr, nullptr, e1b, 1, 1),
            mkseg(r1b, W0t, 2048, 1024, xb,  nullptr, nullptr, nullptr, nullptr, e0b, 1, 1),
            mkseg(r3b, W2t, 512,  2048, r2b, nullptr, nullptr, nullptr, nullptr, e2b, 1, 1));
}